// Round 11
// baseline (138.168 us; speedup 1.0000x reference)
//
#include <hip/hip_runtime.h>

#define NLAYERS 32
#define H 16
#define INDIM 124

typedef __fp16 pk16x2 __attribute__((ext_vector_type(2)));   // cvt_pkrtz result
typedef _Float16 half4 __attribute__((ext_vector_type(4)));
typedef _Float16 half8 __attribute__((ext_vector_type(8)));
typedef float floatx4 __attribute__((ext_vector_type(4)));
typedef float floatx2 __attribute__((ext_vector_type(2)));
typedef int intx2 __attribute__((ext_vector_type(2)));
typedef int intx4 __attribute__((ext_vector_type(4)));

static __device__ __forceinline__ half4 mk_half4(pk16x2 a, pk16x2 b) {
    intx2 v;
    v.x = __builtin_bit_cast(int, a);
    v.y = __builtin_bit_cast(int, b);
    return __builtin_bit_cast(half4, v);
}
static __device__ __forceinline__ half8 mk_half8(pk16x2 a, pk16x2 b,
                                                 pk16x2 c, pk16x2 d) {
    intx4 v;
    v.x = __builtin_bit_cast(int, a);
    v.y = __builtin_bit_cast(int, b);
    v.z = __builtin_bit_cast(int, c);
    v.w = __builtin_bit_cast(int, d);
    return __builtin_bit_cast(half8, v);
}
static __device__ __forceinline__ half4 low_half(half8 v) {
    intx4 i = __builtin_bit_cast(intx4, v);
    intx2 r; r.x = i.x; r.y = i.y;
    return __builtin_bit_cast(half4, r);
}

// Split-f16 MFMA residual MLP (single kernel — cross-kernel d_ws handoff
// proved non-coherent in R10; weights stay block-staged in LDS).
// hT lives in the MFMA D-fragment (m=quad*4+r, n=lane&15) == next B-frag.
// Per residual layer: d = MFMA16(wc.lo, hhi, bias) + one K=32 correction
// MFMA (A' = [WThi|WTlo] interleaved, B' = {hlo, hhi}).
// leaky(x) = 0.6x + 0.4|x|; hlo = h - (h & 0xFFFFE000) = h - f16_rtz(h).
// Bias frags need NO staging: bs + l*16 + q*4 is already fragment-ordered —
// global loads, L1-hit, register-prefetched one layer ahead (as is wc).
// Block = 512 (8 waves), grid = 1024: LDS 40960 B/block -> 4 blocks/CU =
// exactly 160 KiB and 32 waves/CU (max occupancy), single residency round.
__global__ __launch_bounds__(512, 8) void fractal_kernel(
    const float* __restrict__ z, const float* __restrict__ c,
    const float* __restrict__ W1, const float* __restrict__ b1,
    const float* __restrict__ Ws, const float* __restrict__ bs,
    const float* __restrict__ Wf, const float* __restrict__ bf,
    float* __restrict__ out, int B)
{
    __shared__ half8 lds_wc[NLAYERS * 64];   // correction A' frags (hi|lo) 32K
    __shared__ half8 lds_w1hi[4 * 64];       // layer-1 hi A frags          4K
    __shared__ half8 lds_w1lo[4 * 64];       // layer-1 lo A frags          4K

    const int tid = threadIdx.x;
    const int lane = tid & 63;
    const int q = lane >> 4, col = lane & 15;

    // wc (K=32): A'[m][8q+j] = j<4 ? hi(Ws[l][4q+j][m]) : lo(Ws[l][4q+j-4][m])
    for (int idx = tid; idx < NLAYERS * 64; idx += 512) {
        int l = idx >> 6, sl = idx & 63;
        int sq = sl >> 4, scol = sl & 15;
        half8 vc;
#pragma unroll
        for (int j = 0; j < 4; ++j) {
            float w = Ws[l * H * H + (sq * 4 + j) * H + scol];
            _Float16 hi = (_Float16)w;
            vc[j] = hi;                              // slots j<4: hi (pairs hlo)
            vc[j + 4] = (_Float16)(w - (float)hi);   // slots j>=4: lo (pairs hhi)
        }
        lds_wc[idx] = vc;
    }
    // W1^T hi/lo: A[m=col][k] = W1[k][col], k = t*32 + q*8 + j
    if (tid < 256) {
        int t = tid >> 6, sl = tid & 63;
        int sq = sl >> 4, scol = sl & 15;
        half8 vh, vl;
#pragma unroll
        for (int j = 0; j < 8; ++j) {
            int k = t * 32 + sq * 8 + j;
            float w = (k < INDIM) ? W1[k * H + scol] : 0.f;
            _Float16 hi = (_Float16)w;
            vh[j] = hi;
            vl[j] = (_Float16)(w - (float)hi);
        }
        lds_w1hi[tid] = vh;
        lds_w1lo[tid] = vl;
    }
    __syncthreads();

    const int wave = (blockIdx.x * 512 + tid) >> 6;
    const int nwaves = (gridDim.x * 512) >> 6;   // 8192
    const int stride16 = nwaves * 16;            // batch stride between tiles

    constexpr float C_HI = 0.15915494309189535f;                        // fl(1/2pi)
    constexpr float C_LO = (float)(0.15915494309189535 - (double)C_HI); // residual

    const floatx2* z2 = (const floatx2*)z;
    const floatx2* c2 = (const floatx2*)c;
    const floatx4 bias1 = *(const floatx4*)(b1 + q * 4);
    const floatx4 wf4 = *(const floatx4*)(Wf + q * 4);
    const float bff = bf[0];

    const int n0 = wave * 16 + col;
    floatx4 h[4];   // h[i]: master fp32 hidden state for tile i

    // ---- Layer 1: positional encoding + Dense(124->16) per tile ----
#pragma unroll
    for (int i = 0; i < 4; ++i) {
        const int n = n0 + i * stride16;
        floatx2 zz = z2[n], cc = c2[n];
        float xv[4] = {zz.x, zz.y, cc.x, cc.y};

        // two-float x/(2pi): x*2^i exact in fp32, so frac((yh+yl)*2^i) gives
        // an accurate phase for sin(x*2^i) without Payne-Hanek.
        float yh[4], yl[4];
#pragma unroll
        for (int d = 0; d < 4; ++d) {
            yh[d] = xv[d] * C_HI;
            yl[d] = __builtin_fmaf(xv[d], C_HI, -yh[d]) + xv[d] * C_LO;
        }

        floatx4 acc = bias1;
#pragma unroll
        for (int t = 0; t < 4; ++t) {
            // features k = t*32 + q*8 + j: j<4 -> cos(2^(t*4+q-1) x_d),
            // j>=4 -> sin(2^(t*4+q) x_d), d=j&3; t=0,q=0,j<4 -> raw x.
            // k=124..127 hit zeroed A columns — values harmless.
            half8 ah = lds_w1hi[t * 64 + lane];
            half8 al = lds_w1lo[t * 64 + lane];
            const float sc_cos = __builtin_ldexpf(1.0f, t * 4 + q - 1);
            const float sc_sin = __builtin_ldexpf(1.0f, t * 4 + q);
            float fv[8];
#pragma unroll
            for (int j = 0; j < 8; ++j) {
                const int d = j & 3;
                const bool is_cos = (j < 4);
                const float sc = is_cos ? sc_cos : sc_sin;
                float fr = __builtin_amdgcn_fractf(yh[d] * sc);
                fr = __builtin_fmaf(yl[d], sc, fr);
                if (is_cos) fr += 0.25f;                   // cos = sin(+1/4 rev)
                fv[j] = __builtin_amdgcn_sinf(fr);
                if (t == 0 && is_cos && q == 0) fv[j] = xv[j];
            }
            half8 bh = mk_half8(__builtin_amdgcn_cvt_pkrtz(fv[0], fv[1]),
                                __builtin_amdgcn_cvt_pkrtz(fv[2], fv[3]),
                                __builtin_amdgcn_cvt_pkrtz(fv[4], fv[5]),
                                __builtin_amdgcn_cvt_pkrtz(fv[6], fv[7]));
            acc = __builtin_amdgcn_mfma_f32_16x16x32_f16(ah, bh, acc, 0, 0, 0);
            acc = __builtin_amdgcn_mfma_f32_16x16x32_f16(al, bh, acc, 0, 0, 0);
        }
#pragma unroll
        for (int r = 0; r < 4; ++r)
            h[i][r] = fmaxf(acc[r], 0.2f * acc[r]);
    }

    // ---- 32 residual layers, 4 tiles interleaved; next-layer prefetch ----
    half8 wc_nxt = lds_wc[lane];
    floatx4 bias_nxt = *(const floatx4*)(bs + q * 4);
#pragma unroll
    for (int l = 0; l < NLAYERS; ++l) {
        half8 wc = wc_nxt;
        floatx4 bias = bias_nxt;
        if (l + 1 < NLAYERS) {
            wc_nxt = lds_wc[(l + 1) * 64 + lane];
            bias_nxt = *(const floatx4*)(bs + (l + 1) * H + q * 4);
        }
        half4 wh = low_half(wc);          // == hi(Ws^T) fragment, free extract

#pragma unroll
        for (int i = 0; i < 4; ++i) {
            // hi = f16_rtz(h); float(hi) == h & 0xFFFFE000 for normal h.
            half4 hhi = mk_half4(__builtin_amdgcn_cvt_pkrtz(h[i][0], h[i][1]),
                                 __builtin_amdgcn_cvt_pkrtz(h[i][2], h[i][3]));
            intx4 hb = __builtin_bit_cast(intx4, h[i]) & (int)0xFFFFE000;
            floatx4 lo4 = h[i] - __builtin_bit_cast(floatx4, hb);
            intx2 hbits = __builtin_bit_cast(intx2, hhi);
            half8 bp = mk_half8(__builtin_amdgcn_cvt_pkrtz(lo4[0], lo4[1]),
                                __builtin_amdgcn_cvt_pkrtz(lo4[2], lo4[3]),
                                __builtin_bit_cast(pk16x2, hbits.x),
                                __builtin_bit_cast(pk16x2, hbits.y));
            floatx4 d = __builtin_amdgcn_mfma_f32_16x16x16f16(wh, hhi, bias, 0, 0, 0);
            d = __builtin_amdgcn_mfma_f32_16x16x32_f16(wc, bp, d, 0, 0, 0);
            // h += leaky(d) = 0.6d + 0.4|d|  (vector form -> v_pk_fma_f32)
            floatx4 ad = __builtin_bit_cast(floatx4,
                             __builtin_bit_cast(intx4, d) & 0x7FFFFFFF);
            h[i] = h[i] + d * 0.6f + ad * 0.4f;
        }
    }

    // ---- Final Dense(16->1): column n spread over 4 quads ----
#pragma unroll
    for (int i = 0; i < 4; ++i) {
        float p = h[i][0] * wf4.x;
        p = __builtin_fmaf(h[i][1], wf4.y, p);
        p = __builtin_fmaf(h[i][2], wf4.z, p);
        p = __builtin_fmaf(h[i][3], wf4.w, p);
        p += __shfl_xor(p, 16, 64);
        p += __shfl_xor(p, 32, 64);
        if (q == 0) out[n0 + i * stride16] = p + bff;
    }
}

extern "C" void kernel_launch(void* const* d_in, const int* in_sizes, int n_in,
                              void* d_out, int out_size, void* d_ws, size_t ws_size,
                              hipStream_t stream) {
    const float* z  = (const float*)d_in[0];
    const float* c  = (const float*)d_in[1];
    const float* W1 = (const float*)d_in[2];
    const float* b1 = (const float*)d_in[3];
    const float* Ws = (const float*)d_in[4];
    const float* bs = (const float*)d_in[5];
    const float* Wf = (const float*)d_in[6];
    const float* bf = (const float*)d_in[7];
    const int B = in_sizes[0] / 2;  // z is (B,2)

    // 1024 blocks x 8 waves x 4 tiles x 16 = 524288 samples; one residency
    // round at 4 blocks/CU (LDS 40960 x 4 = 160 KiB exactly, 32 waves/CU).
    fractal_kernel<<<1024, 512, 0, stream>>>(z, c, W1, b1, Ws, bs, Wf, bf,
                                             (float*)d_out, B);
}

// Round 14
// 130.017 us; speedup vs baseline: 1.0627x; 1.0627x over previous
//
#include <hip/hip_runtime.h>

#define NLAYERS 32
#define H 16
#define INDIM 124

typedef __fp16 pk16x2 __attribute__((ext_vector_type(2)));   // cvt_pkrtz result
typedef _Float16 half4 __attribute__((ext_vector_type(4)));
typedef _Float16 half8 __attribute__((ext_vector_type(8)));
typedef float floatx4 __attribute__((ext_vector_type(4)));
typedef float floatx2 __attribute__((ext_vector_type(2)));
typedef int intx2 __attribute__((ext_vector_type(2)));
typedef int intx4 __attribute__((ext_vector_type(4)));

static __device__ __forceinline__ half4 mk_half4(pk16x2 a, pk16x2 b) {
    intx2 v;
    v.x = __builtin_bit_cast(int, a);
    v.y = __builtin_bit_cast(int, b);
    return __builtin_bit_cast(half4, v);
}
static __device__ __forceinline__ half8 mk_half8(pk16x2 a, pk16x2 b,
                                                 pk16x2 c, pk16x2 d) {
    intx4 v;
    v.x = __builtin_bit_cast(int, a);
    v.y = __builtin_bit_cast(int, b);
    v.z = __builtin_bit_cast(int, c);
    v.w = __builtin_bit_cast(int, d);
    return __builtin_bit_cast(half8, v);
}
static __device__ __forceinline__ half4 low_half(half8 v) {
    intx4 i = __builtin_bit_cast(intx4, v);
    intx2 r; r.x = i.x; r.y = i.y;
    return __builtin_bit_cast(half4, r);
}

// Split-f16 MFMA residual MLP.  hT lives in the MFMA D-fragment
// (m=quad*4+r, n=lane&15) == the next MFMA's B-fragment layout.
// Per residual layer: d = MFMA16(wc.lo, hhi, bias) then one K=32 correction
// MFMA with A' = column-interleaved [WThi | WTlo] (lds_wc) and
// B' = {hlo[0:4], hhi[0:4]} — merging Whi*hlo + Wlo*hhi into one MFMA.
// The K=16 hi A-operand is the LOW HALF of wc — no separate LDS array.
// leaky(x) = 0.6x + 0.4|x| -> two FMAs (|x| is a free src modifier).
// hlo = h - (h & 0xFFFFE000)  ==  h - float(f16_rtz(h)) for normal h.
// 4 batch tiles per wave share all weight reads.
// LDS = 32K (wc) + 4K (w1hi) + 2K (bias) = 38912 B -> 4 blocks/CU.
// This is the R8 configuration verbatim — the best verified pass
// (absmax 0.0625, ~74 us hot).  R9-R13 mutations all regressed or
// corrupted; do not mutate this body without disasm-level verification.
__global__ __launch_bounds__(256, 4) void fractal_kernel(
    const float* __restrict__ z, const float* __restrict__ c,
    const float* __restrict__ W1, const float* __restrict__ b1,
    const float* __restrict__ Ws, const float* __restrict__ bs,
    const float* __restrict__ Wf, const float* __restrict__ bf,
    float* __restrict__ out, int B)
{
    __shared__ half8 lds_w1hi[4 * 64];       // layer-1 hi A frags
    __shared__ half8 lds_wc[NLAYERS * 64];   // correction A' frags (hi|lo)
    __shared__ floatx4 lds_bs[NLAYERS * 4];  // bias frags

    const int tid = threadIdx.x;
    const int lane = tid & 63;
    const int q = lane >> 4, col = lane & 15;

    // Stage W1^T hi fragments: A[m=col][k] = W1[k][col], k = t*32 + q*8 + j.
    {
        int t = tid >> 6, sl = tid & 63;
        int sq = sl >> 4, scol = sl & 15;
        half8 vh;
#pragma unroll
        for (int j = 0; j < 8; ++j) {
            int k = t * 32 + sq * 8 + j;
            float w = (k < INDIM) ? W1[k * H + scol] : 0.f;
            vh[j] = (_Float16)w;
        }
        lds_w1hi[tid] = vh;
    }
    // Stage correction fragments:
    // wc (K=32): A'[m][8q+j] = j<4 ? hi(Ws[l][4q+j][m]) : lo(Ws[l][4q+j-4][m])
    for (int idx = tid; idx < NLAYERS * 64; idx += 256) {
        int l = idx >> 6, sl = idx & 63;
        int sq = sl >> 4, scol = sl & 15;
        half8 vc;
#pragma unroll
        for (int j = 0; j < 4; ++j) {
            float w = Ws[l * H * H + (sq * 4 + j) * H + scol];
            _Float16 hi = (_Float16)w;
            vc[j] = hi;                              // slots j<4: hi (pairs hlo)
            vc[j + 4] = (_Float16)(w - (float)hi);   // slots j>=4: lo (pairs hhi)
        }
        lds_wc[idx] = vc;
    }
    for (int idx = tid; idx < NLAYERS * 4; idx += 256) {
        int l = idx >> 2, sq = idx & 3;
        floatx4 v;
#pragma unroll
        for (int j = 0; j < 4; ++j) v[j] = bs[l * H + sq * 4 + j];
        lds_bs[idx] = v;
    }

    // Layer-1 LO fragments live in registers (own lane's fragment only).
    half8 w1lo[4];
#pragma unroll
    for (int t = 0; t < 4; ++t) {
#pragma unroll
        for (int j = 0; j < 8; ++j) {
            int k = t * 32 + q * 8 + j;
            float w = (k < INDIM) ? W1[k * H + col] : 0.f;
            _Float16 hi = (_Float16)w;
            w1lo[t][j] = (_Float16)(w - (float)hi);
        }
    }
    __syncthreads();

    const int wave = (blockIdx.x * 256 + tid) >> 6;
    const int nwaves = (gridDim.x * 256) >> 6;   // 8192
    const int stride16 = nwaves * 16;            // batch stride between tiles

    constexpr float C_HI = 0.15915494309189535f;                        // fl(1/2pi)
    constexpr float C_LO = (float)(0.15915494309189535 - (double)C_HI); // residual

    const floatx2* z2 = (const floatx2*)z;
    const floatx2* c2 = (const floatx2*)c;
    const floatx4 bias1 = *(const floatx4*)(b1 + q * 4);
    const floatx4 wf4 = *(const floatx4*)(Wf + q * 4);
    const float bff = bf[0];

    const int n0 = wave * 16 + col;
    float h[4][4];   // h[i][r]: master fp32 hidden state for tile i

    // ---- Layer 1: positional encoding + Dense(124->16) per tile ----
#pragma unroll
    for (int i = 0; i < 4; ++i) {
        const int n = n0 + i * stride16;
        floatx2 zz = z2[n], cc = c2[n];
        float xv[4] = {zz.x, zz.y, cc.x, cc.y};

        // two-float x/(2pi): x*2^i exact in fp32, so frac((yh+yl)*2^i) gives
        // an accurate phase for sin(x*2^i) without Payne-Hanek.
        float yh[4], yl[4];
#pragma unroll
        for (int d = 0; d < 4; ++d) {
            yh[d] = xv[d] * C_HI;
            yl[d] = __builtin_fmaf(xv[d], C_HI, -yh[d]) + xv[d] * C_LO;
        }

        floatx4 acc = bias1;
#pragma unroll
        for (int t = 0; t < 4; ++t) {
            // features k = t*32 + q*8 + j: j<4 -> cos(2^(t*4+q-1) x_d),
            // j>=4 -> sin(2^(t*4+q) x_d), d=j&3; t=0,q=0,j<4 -> raw x.
            // k=124..127 hit zeroed A columns — values harmless.
            const float sc_cos = __builtin_ldexpf(1.0f, t * 4 + q - 1);
            const float sc_sin = __builtin_ldexpf(1.0f, t * 4 + q);
            float fv[8];
#pragma unroll
            for (int j = 0; j < 8; ++j) {
                const int d = j & 3;
                const bool is_cos = (j < 4);
                const float sc = is_cos ? sc_cos : sc_sin;
                float fr = __builtin_amdgcn_fractf(yh[d] * sc);  // exact
                fr = __builtin_fmaf(yl[d], sc, fr);
                if (is_cos) fr += 0.25f;                   // cos = sin(+1/4 rev)
                fv[j] = __builtin_amdgcn_sinf(fr);
                if (t == 0 && is_cos && q == 0) fv[j] = xv[j];
            }
            half8 bh = mk_half8(__builtin_amdgcn_cvt_pkrtz(fv[0], fv[1]),
                                __builtin_amdgcn_cvt_pkrtz(fv[2], fv[3]),
                                __builtin_amdgcn_cvt_pkrtz(fv[4], fv[5]),
                                __builtin_amdgcn_cvt_pkrtz(fv[6], fv[7]));
            half8 ah = lds_w1hi[t * 64 + lane];
            acc = __builtin_amdgcn_mfma_f32_16x16x32_f16(ah, bh, acc, 0, 0, 0);
            acc = __builtin_amdgcn_mfma_f32_16x16x32_f16(w1lo[t], bh, acc, 0, 0, 0);
        }
#pragma unroll
        for (int r = 0; r < 4; ++r)
            h[i][r] = fmaxf(acc[r], 0.2f * acc[r]);
    }

    // ---- 32 residual layers, 4 tiles interleaved ----
#pragma unroll
    for (int l = 0; l < NLAYERS; ++l) {
        half8 wc = lds_wc[l * 64 + lane];
        half4 wh = low_half(wc);          // == hi(Ws^T) fragment, free extract
        floatx4 bias = lds_bs[l * 4 + q];

        floatx4 d4[4];
#pragma unroll
        for (int i = 0; i < 4; ++i) {
            // hi = f16_rtz(h); float(hi) == h & 0xFFFFE000 for normal h.
            half4 hhi = mk_half4(__builtin_amdgcn_cvt_pkrtz(h[i][0], h[i][1]),
                                 __builtin_amdgcn_cvt_pkrtz(h[i][2], h[i][3]));
            float lo[4];
#pragma unroll
            for (int r = 0; r < 4; ++r) {
                unsigned u = __builtin_bit_cast(unsigned, h[i][r]) & 0xFFFFE000u;
                lo[r] = h[i][r] - __builtin_bit_cast(float, u);
            }
            intx2 hbits = __builtin_bit_cast(intx2, hhi);
            half8 bp = mk_half8(__builtin_amdgcn_cvt_pkrtz(lo[0], lo[1]),
                                __builtin_amdgcn_cvt_pkrtz(lo[2], lo[3]),
                                __builtin_bit_cast(pk16x2, hbits.x),
                                __builtin_bit_cast(pk16x2, hbits.y));
            floatx4 d = __builtin_amdgcn_mfma_f32_16x16x16f16(wh, hhi, bias, 0, 0, 0);
            d = __builtin_amdgcn_mfma_f32_16x16x32_f16(wc, bp, d, 0, 0, 0);
            d4[i] = d;
        }
#pragma unroll
        for (int i = 0; i < 4; ++i) {
#pragma unroll
            for (int r = 0; r < 4; ++r) {
                // h += leaky(d) = 0.6d + 0.4|d|
                h[i][r] = __builtin_fmaf(0.6f, d4[i][r], h[i][r]);
                h[i][r] = __builtin_fmaf(0.4f, __builtin_fabsf(d4[i][r]), h[i][r]);
            }
        }
    }

    // ---- Final Dense(16->1): column n spread over 4 quads ----
#pragma unroll
    for (int i = 0; i < 4; ++i) {
        float p = h[i][0] * wf4.x;
        p = __builtin_fmaf(h[i][1], wf4.y, p);
        p = __builtin_fmaf(h[i][2], wf4.z, p);
        p = __builtin_fmaf(h[i][3], wf4.w, p);
        p += __shfl_xor(p, 16, 64);
        p += __shfl_xor(p, 32, 64);
        if (q == 0) out[n0 + i * stride16] = p + bff;
    }
}

extern "C" void kernel_launch(void* const* d_in, const int* in_sizes, int n_in,
                              void* d_out, int out_size, void* d_ws, size_t ws_size,
                              hipStream_t stream) {
    const float* z  = (const float*)d_in[0];
    const float* c  = (const float*)d_in[1];
    const float* W1 = (const float*)d_in[2];
    const float* b1 = (const float*)d_in[3];
    const float* Ws = (const float*)d_in[4];
    const float* bs = (const float*)d_in[5];
    const float* Wf = (const float*)d_in[6];
    const float* bf = (const float*)d_in[7];
    const int B = in_sizes[0] / 2;  // z is (B,2)

    const int blocks = 2048;  // 8192 waves x 4 tiles x 16 = 524288 samples
    fractal_kernel<<<blocks, 256, 0, stream>>>(z, c, W1, b1, Ws, bs, Wf, bf,
                                               (float*)d_out, B);
}